// Round 5
// baseline (246.820 us; speedup 1.0000x reference)
//
#include <hip/hip_runtime.h>

// Problem constants (CausalSelfAttention: B=4 T=2048 C=768 H=KVH=6 D=128)
#define BB 4
#define TT 2048
#define CC 768
#define HH 6
#define DD 128
#define BT (BB * TT)          // 8192 rows
#define HALF 64
#define NBH (BB * HH)         // 24
// combined scale folded into q_t: exp(s/sqrt(128)) = exp2(s * QKSCALE)
#define QKSCALE 0.12753785627919282f   // (1/sqrt(128)) * log2(e)

typedef __bf16 v8bf __attribute__((ext_vector_type(8)));
typedef float f32x4 __attribute__((ext_vector_type(4)));

#if __has_builtin(__builtin_amdgcn_exp2f)
#define EXP2(x) __builtin_amdgcn_exp2f(x)
#else
#define EXP2(x) exp2f(x)
#endif

// ---------------- fp32 -> bf16 (RNE) ----------------
__device__ __forceinline__ unsigned short f2b(float f) {
  union { float f; unsigned u; } v; v.f = f;
  unsigned r = v.u + 0x7FFFu + ((v.u >> 16) & 1u);
  return (unsigned short)(r >> 16);
}
__device__ __forceinline__ float b2f(unsigned short u) {
  union { unsigned u; float f; } v; v.u = (unsigned)u << 16;
  return v.f;
}
// pack two fp32 -> bf16x2 by truncation: 1 v_perm_b32
__device__ __forceinline__ unsigned pk2(float f0, float f1) {
  union { float f; unsigned u; } a, b; a.f = f1; b.f = f0;
  return __builtin_amdgcn_perm(a.u, b.u, 0x07060302u);
}

// async global->LDS, 16B per lane; lds base wave-uniform, deposit at base + lane*16
__device__ __forceinline__ void load_lds16(const void* g, void* l) {
  __builtin_amdgcn_global_load_lds(
      (const __attribute__((address_space(1))) unsigned int*)g,
      (__attribute__((address_space(3))) unsigned int*)(unsigned int)(unsigned long long)(l),
      16, 0, 0);
}

__global__ __launch_bounds__(256) void cvt_f2b_kernel(const float* __restrict__ src,
                                                      unsigned short* __restrict__ dst,
                                                      int n4) {
  int i = blockIdx.x * 256 + threadIdx.x;
  if (i >= n4) return;
  float4 f = ((const float4*)src)[i];
  ushort4 o;
  o.x = f2b(f.x); o.y = f2b(f.y); o.z = f2b(f.z); o.w = f2b(f.w);
  ((ushort4*)dst)[i] = o;
}

// all 4 weights (768x768 each) -> contiguous bf16 wb[4][768*768]
__global__ __launch_bounds__(256) void cvt_w4_kernel(const float* __restrict__ w0,
                                                     const float* __restrict__ w1,
                                                     const float* __restrict__ w2,
                                                     const float* __restrict__ w3,
                                                     unsigned short* __restrict__ dst) {
  int bsel = blockIdx.x / 576;
  int i = (blockIdx.x % 576) * 256 + threadIdx.x;
  const float* src = bsel == 0 ? w0 : bsel == 1 ? w1 : bsel == 2 ? w2 : w3;
  float4 f = ((const float4*)src)[i];
  ushort4 o;
  o.x = f2b(f.x); o.y = f2b(f.y); o.z = f2b(f.z); o.w = f2b(f.w);
  ((ushort4*)(dst + bsel * 589824))[i] = o;
}

// ---------------- fused QKV GEMM (128x128 tile, BK=32, dbuf + swizzled LDS) ----
// grid (64, 18): wsel = by/6 (0=q,1=k,2=v), head h = by%6.
// q,k -> bf16 [bh][t][d] (rope runs in place); v -> bf16 v_t [bh][d][t].
__global__ __launch_bounds__(256) void gemm_qkv(const unsigned short* __restrict__ A,
                                                const unsigned short* __restrict__ Wall,
                                                unsigned short* __restrict__ qb,
                                                unsigned short* __restrict__ kb,
                                                unsigned short* __restrict__ vt) {
  __shared__ __align__(16) unsigned short As[2][512 * 8];
  __shared__ __align__(16) unsigned short Bs[2][512 * 8];
  const int m0 = blockIdx.x * 128;
  const int wsel = blockIdx.y / HH, h = blockIdx.y % HH;
  const unsigned short* W = Wall + (size_t)wsel * 589824 + (size_t)h * 128 * CC;
  const int tid = threadIdx.x;
  const int wave = tid >> 6, lane = tid & 63;
  const int fr = lane & 15, quad = lane >> 4;
  const int wm = (wave & 1) * 64, wn = (wave >> 1) * 64;

  f32x4 acc[4][4];
#pragma unroll
  for (int i = 0; i < 4; i++)
#pragma unroll
    for (int j = 0; j < 4; j++) acc[i][j] = (f32x4){0.f, 0.f, 0.f, 0.f};

  auto stage = [&](int kk, int buf) {
#pragma unroll
    for (int it = 0; it < 2; it++) {
      int base_slot = wave * 128 + it * 64;
      int sigma = base_slot + lane;
      int r = sigma >> 2, g = (sigma & 3) ^ ((r >> 1) & 3);
      load_lds16(A + (size_t)(m0 + r) * CC + kk + g * 8, &As[buf][base_slot * 8]);
      load_lds16(W + (size_t)r * CC + kk + g * 8, &Bs[buf][base_slot * 8]);
    }
  };

  stage(0, 0);
  __syncthreads();
  for (int step = 0; step < CC / 32; step++) {
    int buf = step & 1;
    if (step + 1 < CC / 32) stage((step + 1) * 32, buf ^ 1);
    v8bf af[4], bfr[4];
#pragma unroll
    for (int i = 0; i < 4; i++) {
      int ra = wm + i * 16 + fr;
      af[i] = *(const v8bf*)&As[buf][(4 * ra + (quad ^ ((ra >> 1) & 3))) * 8];
      int rb = wn + i * 16 + fr;
      bfr[i] = *(const v8bf*)&Bs[buf][(4 * rb + (quad ^ ((rb >> 1) & 3))) * 8];
    }
#pragma unroll
    for (int i = 0; i < 4; i++)
#pragma unroll
      for (int j = 0; j < 4; j++)
        acc[i][j] = __builtin_amdgcn_mfma_f32_16x16x32_bf16(af[i], bfr[j], acc[i][j], 0, 0, 0);
    __syncthreads();
  }

  if (wsel < 2) {
    unsigned short* dst = wsel ? kb : qb;
#pragma unroll
    for (int i = 0; i < 4; i++) {
      int rr0 = m0 + wm + i * 16 + quad * 4;
      int b = rr0 >> 11, t0 = rr0 & 2047;
      size_t base = ((size_t)(b * HH + h) * TT + t0) * DD;
#pragma unroll
      for (int j = 0; j < 4; j++) {
        int d = wn + j * 16 + fr;
#pragma unroll
        for (int r = 0; r < 4; r++)
          dst[base + (size_t)r * DD + d] = f2b(acc[i][j][r]);
      }
    }
  } else {
#pragma unroll
    for (int i = 0; i < 4; i++) {
      int rr0 = m0 + wm + i * 16 + quad * 4;
      int b = rr0 >> 11, t0 = rr0 & 2047;
      int bh = b * HH + h;
#pragma unroll
      for (int j = 0; j < 4; j++) {
        int d = wn + j * 16 + fr;
        ushort4 u = { f2b(acc[i][j][0]), f2b(acc[i][j][1]),
                      f2b(acc[i][j][2]), f2b(acc[i][j][3]) };
        *(ushort4*)&vt[((size_t)bh * DD + d) * TT + t0] = u;
      }
    }
  }
}

// ---------------- wproj GEMM: 64x128 tile (768 blocks -> 3/CU) ----------------
__global__ __launch_bounds__(256) void gemm_w64(const unsigned short* __restrict__ A,
                                                const unsigned short* __restrict__ W,
                                                float* __restrict__ C) {
  __shared__ __align__(16) unsigned short As[2][256 * 8];
  __shared__ __align__(16) unsigned short Bs[2][512 * 8];
  const int m0 = blockIdx.x * 64, n0 = blockIdx.y * 128;
  const int tid = threadIdx.x;
  const int wave = tid >> 6, lane = tid & 63;
  const int fr = lane & 15, quad = lane >> 4;
  const int wm = (wave & 1) * 32, wn = (wave >> 1) * 64;

  f32x4 acc[2][4];
#pragma unroll
  for (int i = 0; i < 2; i++)
#pragma unroll
    for (int j = 0; j < 4; j++) acc[i][j] = (f32x4){0.f, 0.f, 0.f, 0.f};

  auto stage = [&](int kk, int buf) {
    {
      int base_slot = wave * 64;
      int sigma = base_slot + lane;
      int r = sigma >> 2, g = (sigma & 3) ^ ((r >> 1) & 3);
      load_lds16(A + (size_t)(m0 + r) * CC + kk + g * 8, &As[buf][base_slot * 8]);
    }
#pragma unroll
    for (int it = 0; it < 2; it++) {
      int base_slot = wave * 128 + it * 64;
      int sigma = base_slot + lane;
      int r = sigma >> 2, g = (sigma & 3) ^ ((r >> 1) & 3);
      load_lds16(W + (size_t)(n0 + r) * CC + kk + g * 8, &Bs[buf][base_slot * 8]);
    }
  };

  stage(0, 0);
  __syncthreads();
  for (int step = 0; step < CC / 32; step++) {
    int buf = step & 1;
    if (step + 1 < CC / 32) stage((step + 1) * 32, buf ^ 1);
    v8bf af[2], bfr[4];
#pragma unroll
    for (int i = 0; i < 2; i++) {
      int ra = wm + i * 16 + fr;
      af[i] = *(const v8bf*)&As[buf][(4 * ra + (quad ^ ((ra >> 1) & 3))) * 8];
    }
#pragma unroll
    for (int j = 0; j < 4; j++) {
      int rb = wn + j * 16 + fr;
      bfr[j] = *(const v8bf*)&Bs[buf][(4 * rb + (quad ^ ((rb >> 1) & 3))) * 8];
    }
#pragma unroll
    for (int i = 0; i < 2; i++)
#pragma unroll
      for (int j = 0; j < 4; j++)
        acc[i][j] = __builtin_amdgcn_mfma_f32_16x16x32_bf16(af[i], bfr[j], acc[i][j], 0, 0, 0);
    __syncthreads();
  }

  const int orow = m0 + wm + quad * 4;
#pragma unroll
  for (int i = 0; i < 2; i++)
#pragma unroll
    for (int j = 0; j < 4; j++) {
      int oc = n0 + wn + j * 16 + fr;
#pragma unroll
      for (int r = 0; r < 4; r++)
        C[(size_t)(orow + i * 16 + r) * CC + oc] = acc[i][j][r];
    }
}

// ---------------- RoPE + sample-var norm, in place on bf16 [bh][t][d] ----------
// scale: QKSCALE for q (folds softmax scale), 1.0 for k.
__global__ __launch_bounds__(256) void rope_norm_kernel(unsigned short* __restrict__ qk,
                                                        const float* __restrict__ cosb,
                                                        const float* __restrict__ sinb,
                                                        float scale) {
  int idx = blockIdx.x * 4 + (threadIdx.x >> 6);   // bh*T + t
  int lane = threadIdx.x & 63;
  int tpos = idx & (TT - 1);
  size_t base = (size_t)idx * DD;

  float x1 = b2f(qk[base + lane]);
  float x2 = b2f(qk[base + HALF + lane]);
  float c = cosb[tpos * HALF + lane];
  float s = sinb[tpos * HALF + lane];
  float o1 = x1 * c + x2 * s;
  float o2 = x2 * c - x1 * s;

  float sum = o1 + o2;
#pragma unroll
  for (int off = 32; off; off >>= 1) sum += __shfl_xor(sum, off);
  float mean = sum * (1.f / 128.f);
  float d1 = o1 - mean, d2 = o2 - mean;
  float vs = d1 * d1 + d2 * d2;
#pragma unroll
  for (int off = 32; off; off >>= 1) vs += __shfl_xor(vs, off);
  float inv = scale / (sqrtf(vs * (1.f / 127.f)) + 1e-6f);

  qk[base + lane] = f2b(d1 * inv);
  qk[base + HALF + lane] = f2b(d2 * inv);
}

// ---------------- MFMA flash attention, fine split-K (causal, no-max) ----------
// 1920 blocks x 256 thr (4 waves, wave = 16 Q-rows, block = 64 rows).
// Unit = (qt, chunk c of <=16 K-tiles); partials combine by ADDITION (no-max
// softmax; QKSCALE pre-folded into q). l accumulated via MFMA against ones.
// P packed by truncating v_perm. Partial O stored bf16, l fp32.
__global__ __launch_bounds__(256) void attn_mfma(const unsigned short* __restrict__ qtb,
                                                 const unsigned short* __restrict__ ktb,
                                                 const unsigned short* __restrict__ vtb,
                                                 unsigned short* __restrict__ Opart,
                                                 float* __restrict__ lpart) {
  __shared__ __align__(16) unsigned short Ks[2][512 * 8];   // 32 x 128 bf16
  __shared__ __align__(16) unsigned short Vts[2][512 * 8];  // 128 x 32 bf16 (V^T)
  __shared__ __align__(16) unsigned short Ps[4][16][40];    // per-wave P, pad 40

  const int u = blockIdx.x;
  const int bh = u % NBH;
  const int uu = u / NBH;                         // 0..79, heavy-first
  int qt, c;
  if (uu < 32)      { qt = 31 - (uu >> 2);        c = uu & 3; }
  else if (uu < 56) { int k = uu - 32; int q3 = k / 3; qt = 23 - q3; c = k - q3 * 3; }
  else if (uu < 72) { int k = uu - 56; qt = 15 - (k >> 1); c = k & 1; }
  else              { qt = 7 - (uu - 72);         c = 0; }
  const int t0 = c * 16;
  const int t1 = min(t0 + 16, 2 * qt + 2);
  const int niter = t1 - t0;

  const int tid = threadIdx.x;
  const int wave = tid >> 6, lane = tid & 63;
  const int fr = lane & 15, quad = lane >> 4;
  const size_t head_base = (size_t)bh * TT * DD;
  const int m0 = qt * 64 + wave * 16;             // wave's 16 Q rows

  v8bf qf[4];
#pragma unroll
  for (int kbk = 0; kbk < 4; kbk++)
    qf[kbk] = *(const v8bf*)(qtb + head_base + (size_t)(m0 + fr) * DD + kbk * 32 + quad * 8);

  const __bf16 one_bf = (__bf16)1.0f;
  v8bf ones = {one_bf, one_bf, one_bf, one_bf, one_bf, one_bf, one_bf, one_bf};

  f32x4 oacc[8];
#pragma unroll
  for (int i = 0; i < 8; i++) oacc[i] = (f32x4){0.f, 0.f, 0.f, 0.f};
  f32x4 lacc = (f32x4){0.f, 0.f, 0.f, 0.f};

  auto stage = [&](int jt, int buf) {
    const unsigned short* kbase = ktb + head_base + (size_t)(jt * 32) * DD;
    const unsigned short* vbase = vtb + head_base + jt * 32;
#pragma unroll
    for (int it = 0; it < 2; it++) {
      int base_slot = it * 256 + wave * 64;
      int sigma = base_slot + lane;
      int s = sigma >> 4, gk = (sigma & 15) ^ (s & 7);
      load_lds16(kbase + (size_t)s * DD + gk * 8, &Ks[buf][base_slot * 8]);
      int d = sigma >> 2, gv = (sigma & 3) ^ ((d >> 1) & 3);
      load_lds16(vbase + (size_t)d * TT + gv * 8, &Vts[buf][base_slot * 8]);
    }
  };

  stage(t0, 0);
  __syncthreads();

  for (int it = 0; it < niter; it++) {
    const int jt = t0 + it;
    const int buf = it & 1;
    if (it + 1 < niter) stage(jt + 1, buf ^ 1);

    const int j0 = jt * 32;
    if (j0 <= m0 + 15) {             // wave not fully masked (uniform)
      f32x4 st0 = (f32x4){0.f, 0.f, 0.f, 0.f}, st1 = (f32x4){0.f, 0.f, 0.f, 0.f};
#pragma unroll
      for (int kbk = 0; kbk < 4; kbk++) {
        int g = 4 * kbk + quad;
        v8bf a0 = *(const v8bf*)&Ks[buf][(16 * fr + (g ^ (fr & 7))) * 8];
        v8bf a1 = *(const v8bf*)&Ks[buf][(16 * (fr + 16) + (g ^ (fr & 7))) * 8];
        st0 = __builtin_amdgcn_mfma_f32_16x16x32_bf16(a0, qf[kbk], st0, 0, 0, 0);
        st1 = __builtin_amdgcn_mfma_f32_16x16x32_bf16(a1, qf[kbk], st1, 0, 0, 0);
      }

      float p[8];
      if (j0 + 31 > m0) {            // diagonal tile: mask (uniform branch)
        const int qrow = m0 + fr;
#pragma unroll
        for (int r = 0; r < 4; r++) {
          int c0 = j0 + quad * 4 + r;
          p[r]     = (c0      <= qrow) ? EXP2(st0[r]) : 0.f;
          p[4 + r] = (c0 + 16 <= qrow) ? EXP2(st1[r]) : 0.f;
        }
      } else {
#pragma unroll
        for (int r = 0; r < 4; r++) { p[r] = EXP2(st0[r]); p[4 + r] = EXP2(st1[r]); }
      }
      uint2 w0 = { pk2(p[0], p[1]), pk2(p[2], p[3]) };
      uint2 w1 = { pk2(p[4], p[5]), pk2(p[6], p[7]) };
      *(uint2*)&Ps[wave][fr][quad * 4] = w0;
      *(uint2*)&Ps[wave][fr][16 + quad * 4] = w1;

      v8bf pa = *(const v8bf*)&Ps[wave][fr][quad * 8];
#pragma unroll
      for (int nt2 = 0; nt2 < 8; nt2++) {
        int d = nt2 * 16 + fr;
        v8bf vb = *(const v8bf*)&Vts[buf][(4 * d + (quad ^ ((d >> 1) & 3))) * 8];
        oacc[nt2] = __builtin_amdgcn_mfma_f32_16x16x32_bf16(pa, vb, oacc[nt2], 0, 0, 0);
      }
      lacc = __builtin_amdgcn_mfma_f32_16x16x32_bf16(pa, ones, lacc, 0, 0, 0);
    }
    __syncthreads();
  }

  // partial write: rows m0 + quad*4 + r, col d = nt2*16 + fr; bf16 O, fp32 l
  unsigned short* Oc = Opart + (size_t)c * (NBH * TT * DD) + head_base;
#pragma unroll
  for (int nt2 = 0; nt2 < 8; nt2++)
#pragma unroll
    for (int r = 0; r < 4; r++)
      Oc[(size_t)(m0 + quad * 4 + r) * DD + nt2 * 16 + fr] = f2b(oacc[nt2][r]);
  if (fr == 0) {
#pragma unroll
    for (int r = 0; r < 4; r++)
      lpart[c * (NBH * TT) + bh * TT + m0 + quad * 4 + r] = lacc[r];
  }
}

// ---------------- combine: yb = (sum_c O_c)/(sum_c l_c), bf16 [bt][C] ----------
__global__ __launch_bounds__(256) void combine_kernel(const unsigned short* __restrict__ Opart,
                                                      const float* __restrict__ lpart,
                                                      unsigned short* __restrict__ yb) {
  int idx = blockIdx.x * 256 + threadIdx.x;    // 1,572,864 threads, 4 elems each
  int row = idx >> 5;                          // bh*2048 + t
  int dg = (idx & 31) * 4;
  int t = row & 2047;
  int qt = t >> 6;
  int nc = (2 * qt + 2 + 15) >> 4;             // chunks written for this row

  float a0 = 0.f, a1 = 0.f, a2 = 0.f, a3 = 0.f, l = 0.f;
  for (int cchunk = 0; cchunk < nc; cchunk++) {
    ushort4 o = *(const ushort4*)&Opart[(size_t)cchunk * (NBH * TT * DD) + (size_t)row * DD + dg];
    a0 += b2f(o.x); a1 += b2f(o.y); a2 += b2f(o.z); a3 += b2f(o.w);
    l += lpart[cchunk * (NBH * TT) + row];
  }
  float linv = 1.f / l;
  int bh = row >> 11;
  int b = bh / HH, h = bh % HH;
  ushort4 u = { f2b(a0 * linv), f2b(a1 * linv), f2b(a2 * linv), f2b(a3 * linv) };
  *(ushort4*)&yb[((size_t)(b * TT + t)) * CC + h * DD + dg] = u;
}

// ---------------- launch ----------------
extern "C" void kernel_launch(void* const* d_in, const int* in_sizes, int n_in,
                              void* d_out, int out_size, void* d_ws, size_t ws_size,
                              hipStream_t stream) {
  const float* x     = (const float*)d_in[0];
  const float* cosb  = (const float*)d_in[1];
  const float* sinb  = (const float*)d_in[2];
  const float* wq    = (const float*)d_in[3];
  const float* wk    = (const float*)d_in[4];
  const float* wv    = (const float*)d_in[5];
  const float* wproj = (const float*)d_in[6];
  float* out = (float*)d_out;

  // workspace layout (117,964,800 B exactly):
  //   0         : q_t bf16 [bh][t][d] (12,582,912)
  //   12582912  : k_t bf16 [bh][t][d] (12,582,912)
  //   25165824  : v_t bf16 [bh][d][t] (12,582,912)
  //   37748736  : yb  bf16 [bt][C]    (12,582,912)
  //   50331648  : xb  bf16 (12,582,912) -> dead after gemm_qkv -> lpart (786,432)
  //   62914560  : wb  bf16 4x589824 elems (4,718,592)
  //   67633152  : Opart bf16 4 chunks x [bh][t][d] (50,331,648)
  char* w = (char*)d_ws;
  unsigned short* q_t   = (unsigned short*)(w);
  unsigned short* k_t   = (unsigned short*)(w + 12582912);
  unsigned short* v_t   = (unsigned short*)(w + 25165824);
  unsigned short* yb    = (unsigned short*)(w + 37748736);
  unsigned short* xb    = (unsigned short*)(w + 50331648);
  float*          lpart = (float*)(w + 50331648);   // alias xb (dead after gemm_qkv)
  unsigned short* wb    = (unsigned short*)(w + 62914560);
  unsigned short* Opart = (unsigned short*)(w + 67633152);

  const int nx4 = BT * CC / 4;   // 1572864

  cvt_f2b_kernel<<<nx4 / 256, 256, 0, stream>>>(x, xb, nx4);
  cvt_w4_kernel<<<2304, 256, 0, stream>>>(wq, wk, wv, wproj, wb);

  gemm_qkv<<<dim3(BT / 128, 3 * HH), 256, 0, stream>>>(xb, wb, q_t, k_t, v_t);

  int nvec = NBH * TT;  // 49152
  rope_norm_kernel<<<nvec / 4, 256, 0, stream>>>(q_t, cosb, sinb, QKSCALE);
  rope_norm_kernel<<<nvec / 4, 256, 0, stream>>>(k_t, cosb, sinb, 1.0f);

  attn_mfma<<<1920, 256, 0, stream>>>(q_t, k_t, v_t, Opart, lpart);
  combine_kernel<<<6144, 256, 0, stream>>>(Opart, lpart, yb);

  gemm_w64<<<dim3(BT / 64, CC / 128), 256, 0, stream>>>(yb, wb + 3 * 589824, out);
}

// Round 6
// 244.393 us; speedup vs baseline: 1.0099x; 1.0099x over previous
//
#include <hip/hip_runtime.h>

// Problem constants (CausalSelfAttention: B=4 T=2048 C=768 H=KVH=6 D=128)
#define BB 4
#define TT 2048
#define CC 768
#define HH 6
#define DD 128
#define BT (BB * TT)          // 8192 rows
#define HALF 64
#define NBH (BB * HH)         // 24
// combined scale folded into q_t: exp(s/sqrt(128)) = exp2(s * QKSCALE)
#define QKSCALE 0.12753785627919282f   // (1/sqrt(128)) * log2(e)

typedef __bf16 v8bf __attribute__((ext_vector_type(8)));
typedef float f32x4 __attribute__((ext_vector_type(4)));

// ---------------- fp32 -> bf16 (RNE) ----------------
__device__ __forceinline__ unsigned short f2b(float f) {
  union { float f; unsigned u; } v; v.f = f;
  unsigned r = v.u + 0x7FFFu + ((v.u >> 16) & 1u);
  return (unsigned short)(r >> 16);
}
__device__ __forceinline__ float b2f(unsigned short u) {
  union { unsigned u; float f; } v; v.u = (unsigned)u << 16;
  return v.f;
}
// pack two fp32 -> bf16x2 by truncation: 1 v_perm_b32
__device__ __forceinline__ unsigned pk2(float f0, float f1) {
  union { float f; unsigned u; } a, b; a.f = f1; b.f = f0;
  return __builtin_amdgcn_perm(a.u, b.u, 0x07060302u);
}

// async global->LDS, 16B per lane; lds base wave-uniform, deposit at base + lane*16
__device__ __forceinline__ void load_lds16(const void* g, void* l) {
  __builtin_amdgcn_global_load_lds(
      (const __attribute__((address_space(1))) unsigned int*)g,
      (__attribute__((address_space(3))) unsigned int*)(unsigned int)(unsigned long long)(l),
      16, 0, 0);
}

// ---------------- merged cvt: x (6144 blocks) + 4 weights (2304 blocks) -------
__global__ __launch_bounds__(256) void cvt_all_kernel(const float* __restrict__ x,
                                                      const float* __restrict__ w0,
                                                      const float* __restrict__ w1,
                                                      const float* __restrict__ w2,
                                                      const float* __restrict__ w3,
                                                      unsigned short* __restrict__ xb,
                                                      unsigned short* __restrict__ wb) {
  int bx = blockIdx.x;
  const float* src;
  unsigned short* dst;
  int i;
  if (bx < 6144) {
    src = x; dst = xb; i = bx * 256 + threadIdx.x;
  } else {
    int bsel = (bx - 6144) / 576;
    src = bsel == 0 ? w0 : bsel == 1 ? w1 : bsel == 2 ? w2 : w3;
    dst = wb + bsel * 589824;
    i = ((bx - 6144) % 576) * 256 + threadIdx.x;
  }
  float4 f = ((const float4*)src)[i];
  ushort4 o;
  o.x = f2b(f.x); o.y = f2b(f.y); o.z = f2b(f.z); o.w = f2b(f.w);
  ((ushort4*)dst)[i] = o;
}

// ---------------- fused QKV GEMM (128x128 tile, BK=32, dbuf + swizzled LDS) ----
// grid (64, 18): wsel = by/6 (0=q,1=k,2=v), head h = by%6.
// q,k -> bf16 [bh][t][d] (rope runs in place); v -> bf16 v_t [bh][d][t].
__global__ __launch_bounds__(256) void gemm_qkv(const unsigned short* __restrict__ A,
                                                const unsigned short* __restrict__ Wall,
                                                unsigned short* __restrict__ qb,
                                                unsigned short* __restrict__ kb,
                                                unsigned short* __restrict__ vt) {
  __shared__ __align__(16) unsigned short As[2][512 * 8];
  __shared__ __align__(16) unsigned short Bs[2][512 * 8];
  const int m0 = blockIdx.x * 128;
  const int wsel = blockIdx.y / HH, h = blockIdx.y % HH;
  const unsigned short* W = Wall + (size_t)wsel * 589824 + (size_t)h * 128 * CC;
  const int tid = threadIdx.x;
  const int wave = tid >> 6, lane = tid & 63;
  const int fr = lane & 15, quad = lane >> 4;
  const int wm = (wave & 1) * 64, wn = (wave >> 1) * 64;

  f32x4 acc[4][4];
#pragma unroll
  for (int i = 0; i < 4; i++)
#pragma unroll
    for (int j = 0; j < 4; j++) acc[i][j] = (f32x4){0.f, 0.f, 0.f, 0.f};

  auto stage = [&](int kk, int buf) {
#pragma unroll
    for (int it = 0; it < 2; it++) {
      int base_slot = wave * 128 + it * 64;
      int sigma = base_slot + lane;
      int r = sigma >> 2, g = (sigma & 3) ^ ((r >> 1) & 3);
      load_lds16(A + (size_t)(m0 + r) * CC + kk + g * 8, &As[buf][base_slot * 8]);
      load_lds16(W + (size_t)r * CC + kk + g * 8, &Bs[buf][base_slot * 8]);
    }
  };

  stage(0, 0);
  __syncthreads();
  for (int step = 0; step < CC / 32; step++) {
    int buf = step & 1;
    if (step + 1 < CC / 32) stage((step + 1) * 32, buf ^ 1);
    v8bf af[4], bfr[4];
#pragma unroll
    for (int i = 0; i < 4; i++) {
      int ra = wm + i * 16 + fr;
      af[i] = *(const v8bf*)&As[buf][(4 * ra + (quad ^ ((ra >> 1) & 3))) * 8];
      int rb = wn + i * 16 + fr;
      bfr[i] = *(const v8bf*)&Bs[buf][(4 * rb + (quad ^ ((rb >> 1) & 3))) * 8];
    }
#pragma unroll
    for (int i = 0; i < 4; i++)
#pragma unroll
      for (int j = 0; j < 4; j++)
        acc[i][j] = __builtin_amdgcn_mfma_f32_16x16x32_bf16(af[i], bfr[j], acc[i][j], 0, 0, 0);
    __syncthreads();
  }

  if (wsel < 2) {
    unsigned short* dst = wsel ? kb : qb;
#pragma unroll
    for (int i = 0; i < 4; i++) {
      int rr0 = m0 + wm + i * 16 + quad * 4;
      int b = rr0 >> 11, t0 = rr0 & 2047;
      size_t base = ((size_t)(b * HH + h) * TT + t0) * DD;
#pragma unroll
      for (int j = 0; j < 4; j++) {
        int d = wn + j * 16 + fr;
#pragma unroll
        for (int r = 0; r < 4; r++)
          dst[base + (size_t)r * DD + d] = f2b(acc[i][j][r]);
      }
    }
  } else {
#pragma unroll
    for (int i = 0; i < 4; i++) {
      int rr0 = m0 + wm + i * 16 + quad * 4;
      int b = rr0 >> 11, t0 = rr0 & 2047;
      int bh = b * HH + h;
#pragma unroll
      for (int j = 0; j < 4; j++) {
        int d = wn + j * 16 + fr;
        ushort4 u = { f2b(acc[i][j][0]), f2b(acc[i][j][1]),
                      f2b(acc[i][j][2]), f2b(acc[i][j][3]) };
        *(ushort4*)&vt[((size_t)bh * DD + d) * TT + t0] = u;
      }
    }
  }
}

// ---------------- wproj GEMM: 64x128 tile (768 blocks -> 3/CU) ----------------
__global__ __launch_bounds__(256) void gemm_w64(const unsigned short* __restrict__ A,
                                                const unsigned short* __restrict__ W,
                                                float* __restrict__ C) {
  __shared__ __align__(16) unsigned short As[2][256 * 8];
  __shared__ __align__(16) unsigned short Bs[2][512 * 8];
  const int m0 = blockIdx.x * 64, n0 = blockIdx.y * 128;
  const int tid = threadIdx.x;
  const int wave = tid >> 6, lane = tid & 63;
  const int fr = lane & 15, quad = lane >> 4;
  const int wm = (wave & 1) * 32, wn = (wave >> 1) * 64;

  f32x4 acc[2][4];
#pragma unroll
  for (int i = 0; i < 2; i++)
#pragma unroll
    for (int j = 0; j < 4; j++) acc[i][j] = (f32x4){0.f, 0.f, 0.f, 0.f};

  auto stage = [&](int kk, int buf) {
    {
      int base_slot = wave * 64;
      int sigma = base_slot + lane;
      int r = sigma >> 2, g = (sigma & 3) ^ ((r >> 1) & 3);
      load_lds16(A + (size_t)(m0 + r) * CC + kk + g * 8, &As[buf][base_slot * 8]);
    }
#pragma unroll
    for (int it = 0; it < 2; it++) {
      int base_slot = wave * 128 + it * 64;
      int sigma = base_slot + lane;
      int r = sigma >> 2, g = (sigma & 3) ^ ((r >> 1) & 3);
      load_lds16(W + (size_t)(n0 + r) * CC + kk + g * 8, &Bs[buf][base_slot * 8]);
    }
  };

  stage(0, 0);
  __syncthreads();
  for (int step = 0; step < CC / 32; step++) {
    int buf = step & 1;
    if (step + 1 < CC / 32) stage((step + 1) * 32, buf ^ 1);
    v8bf af[2], bfr[4];
#pragma unroll
    for (int i = 0; i < 2; i++) {
      int ra = wm + i * 16 + fr;
      af[i] = *(const v8bf*)&As[buf][(4 * ra + (quad ^ ((ra >> 1) & 3))) * 8];
    }
#pragma unroll
    for (int j = 0; j < 4; j++) {
      int rb = wn + j * 16 + fr;
      bfr[j] = *(const v8bf*)&Bs[buf][(4 * rb + (quad ^ ((rb >> 1) & 3))) * 8];
    }
#pragma unroll
    for (int i = 0; i < 2; i++)
#pragma unroll
      for (int j = 0; j < 4; j++)
        acc[i][j] = __builtin_amdgcn_mfma_f32_16x16x32_bf16(af[i], bfr[j], acc[i][j], 0, 0, 0);
    __syncthreads();
  }

  const int orow = m0 + wm + quad * 4;
#pragma unroll
  for (int i = 0; i < 2; i++)
#pragma unroll
    for (int j = 0; j < 4; j++) {
      int oc = n0 + wn + j * 16 + fr;
#pragma unroll
      for (int r = 0; r < 4; r++)
        C[(size_t)(orow + i * 16 + r) * CC + oc] = acc[i][j][r];
    }
}

// ---------------- RoPE + sample-var norm, in place, q and k in one launch -----
__global__ __launch_bounds__(256) void rope_all_kernel(unsigned short* __restrict__ qb,
                                                       unsigned short* __restrict__ kb,
                                                       const float* __restrict__ cosb,
                                                       const float* __restrict__ sinb) {
  int bx = blockIdx.x;
  unsigned short* qk = (bx < 12288) ? qb : kb;
  float scale = (bx < 12288) ? QKSCALE : 1.0f;
  int idx = (bx % 12288) * 4 + (threadIdx.x >> 6);   // bh*T + t
  int lane = threadIdx.x & 63;
  int tpos = idx & (TT - 1);
  size_t base = (size_t)idx * DD;

  float x1 = b2f(qk[base + lane]);
  float x2 = b2f(qk[base + HALF + lane]);
  float c = cosb[tpos * HALF + lane];
  float s = sinb[tpos * HALF + lane];
  float o1 = x1 * c + x2 * s;
  float o2 = x2 * c - x1 * s;

  float sum = o1 + o2;
#pragma unroll
  for (int off = 32; off; off >>= 1) sum += __shfl_xor(sum, off);
  float mean = sum * (1.f / 128.f);
  float d1 = o1 - mean, d2 = o2 - mean;
  float vs = d1 * d1 + d2 * d2;
#pragma unroll
  for (int off = 32; off; off >>= 1) vs += __shfl_xor(vs, off);
  float inv = scale / (sqrtf(vs * (1.f / 127.f)) + 1e-6f);

  qk[base + lane] = f2b(d1 * inv);
  qk[base + HALF + lane] = f2b(d2 * inv);
}

// ---------------- MFMA flash attention v4: 128-row blocks, 32 rows/wave -------
// 960 blocks x 256 thr. Block = 128 Q-rows (qt in 0..15), wave = 32 rows
// (2 fr-sets qs). K/V LDS frag reads amortize over 2x rows vs R5: per
// block-iter 88 KB LDS serves 128 rows -> floor ~14.6 us. Split-K chunks of
// <=16 K-tiles; no-max softmax partials combine by addition. l via MFMA(ones).
__global__ __launch_bounds__(256) void attn_mfma(const unsigned short* __restrict__ qtb,
                                                 const unsigned short* __restrict__ ktb,
                                                 const unsigned short* __restrict__ vtb,
                                                 unsigned short* __restrict__ Opart,
                                                 float* __restrict__ lpart) {
  __shared__ __align__(16) unsigned short Ks[2][512 * 8];   // 32 x 128 bf16
  __shared__ __align__(16) unsigned short Vts[2][512 * 8];  // 128 x 32 bf16 (V^T)
  __shared__ __align__(16) unsigned short Ps[4][32][40];    // per-wave P (2 qs), pad 40

  const int u = blockIdx.x;
  const int bh = u % NBH;
  const int uu = u / NBH;                         // 0..39, heavy-first
  int qt, c;
  if (uu < 16)      { qt = 15 - (uu >> 2); c = uu & 3; }
  else if (uu < 28) { int k = uu - 16; int q3 = k / 3; qt = 11 - q3; c = k - q3 * 3; }
  else if (uu < 36) { int k = uu - 28; qt = 7 - (k >> 1); c = k & 1; }
  else              { qt = 3 - (uu - 36); c = 0; }
  const int t0 = c * 16;
  const int t1 = min(t0 + 16, 4 * qt + 4);
  const int niter = t1 - t0;

  const int tid = threadIdx.x;
  const int wave = tid >> 6, lane = tid & 63;
  const int fr = lane & 15, quad = lane >> 4;
  const size_t head_base = (size_t)bh * TT * DD;
  const int m0 = qt * 128 + wave * 32;            // wave's 32 Q rows

  v8bf qf[2][4];
#pragma unroll
  for (int qs = 0; qs < 2; qs++)
#pragma unroll
    for (int kbk = 0; kbk < 4; kbk++)
      qf[qs][kbk] = *(const v8bf*)(qtb + head_base +
                                   (size_t)(m0 + qs * 16 + fr) * DD + kbk * 32 + quad * 8);

  const __bf16 one_bf = (__bf16)1.0f;
  v8bf ones = {one_bf, one_bf, one_bf, one_bf, one_bf, one_bf, one_bf, one_bf};

  f32x4 oacc[2][8];
#pragma unroll
  for (int qs = 0; qs < 2; qs++)
#pragma unroll
    for (int i = 0; i < 8; i++) oacc[qs][i] = (f32x4){0.f, 0.f, 0.f, 0.f};
  f32x4 lacc[2] = {(f32x4){0.f, 0.f, 0.f, 0.f}, (f32x4){0.f, 0.f, 0.f, 0.f}};

  auto stage = [&](int jt, int buf) {
    const unsigned short* kbase = ktb + head_base + (size_t)(jt * 32) * DD;
    const unsigned short* vbase = vtb + head_base + jt * 32;
#pragma unroll
    for (int it = 0; it < 2; it++) {
      int base_slot = it * 256 + wave * 64;
      int sigma = base_slot + lane;
      int s = sigma >> 4, gk = (sigma & 15) ^ (s & 7);
      load_lds16(kbase + (size_t)s * DD + gk * 8, &Ks[buf][base_slot * 8]);
      int d = sigma >> 2, gv = (sigma & 3) ^ ((d >> 1) & 3);
      load_lds16(vbase + (size_t)d * TT + gv * 8, &Vts[buf][base_slot * 8]);
    }
  };

  stage(t0, 0);
  __syncthreads();

  for (int it = 0; it < niter; it++) {
    const int jt = t0 + it;
    const int buf = it & 1;
    if (it + 1 < niter) stage(jt + 1, buf ^ 1);

    const int j0 = jt * 32;
    if (j0 <= m0 + 31) {             // wave has unmasked rows (uniform branch)
      // S^T: D[m = K-col][n = Q-row]; K-frags shared across both qs sets
      f32x4 st[2][2];
#pragma unroll
      for (int qs = 0; qs < 2; qs++) { st[qs][0] = (f32x4){0,0,0,0}; st[qs][1] = (f32x4){0,0,0,0}; }
#pragma unroll
      for (int kbk = 0; kbk < 4; kbk++) {
        int g = 4 * kbk + quad;
        v8bf a0 = *(const v8bf*)&Ks[buf][(16 * fr + (g ^ (fr & 7))) * 8];
        v8bf a1 = *(const v8bf*)&Ks[buf][(16 * (fr + 16) + (g ^ (fr & 7))) * 8];
        st[0][0] = __builtin_amdgcn_mfma_f32_16x16x32_bf16(a0, qf[0][kbk], st[0][0], 0, 0, 0);
        st[0][1] = __builtin_amdgcn_mfma_f32_16x16x32_bf16(a1, qf[0][kbk], st[0][1], 0, 0, 0);
        st[1][0] = __builtin_amdgcn_mfma_f32_16x16x32_bf16(a0, qf[1][kbk], st[1][0], 0, 0, 0);
        st[1][1] = __builtin_amdgcn_mfma_f32_16x16x32_bf16(a1, qf[1][kbk], st[1][1], 0, 0, 0);
      }

      const bool diag = (j0 + 31 > m0);   // at most 1 tile per wave (uniform)
#pragma unroll
      for (int qs = 0; qs < 2; qs++) {
        float p[8];
        if (diag) {
          const int qrow = m0 + qs * 16 + fr;
#pragma unroll
          for (int r = 0; r < 4; r++) {
            int c0 = j0 + quad * 4 + r;
            p[r]     = (c0      <= qrow) ? exp2f(st[qs][0][r]) : 0.f;
            p[4 + r] = (c0 + 16 <= qrow) ? exp2f(st[qs][1][r]) : 0.f;
          }
        } else {
#pragma unroll
          for (int r = 0; r < 4; r++) { p[r] = exp2f(st[qs][0][r]); p[4 + r] = exp2f(st[qs][1][r]); }
        }
        uint2 w0 = { pk2(p[0], p[1]), pk2(p[2], p[3]) };
        uint2 w1 = { pk2(p[4], p[5]), pk2(p[6], p[7]) };
        *(uint2*)&Ps[wave][qs * 16 + fr][quad * 4] = w0;
        *(uint2*)&Ps[wave][qs * 16 + fr][16 + quad * 4] = w1;
      }

      // PV + l: V-frags shared across both qs sets
      v8bf pa0 = *(const v8bf*)&Ps[wave][fr][quad * 8];
      v8bf pa1 = *(const v8bf*)&Ps[wave][16 + fr][quad * 8];
#pragma unroll
      for (int nt2 = 0; nt2 < 8; nt2++) {
        int d = nt2 * 16 + fr;
        v8bf vb = *(const v8bf*)&Vts[buf][(4 * d + (quad ^ ((d >> 1) & 3))) * 8];
        oacc[0][nt2] = __builtin_amdgcn_mfma_f32_16x16x32_bf16(pa0, vb, oacc[0][nt2], 0, 0, 0);
        oacc[1][nt2] = __builtin_amdgcn_mfma_f32_16x16x32_bf16(pa1, vb, oacc[1][nt2], 0, 0, 0);
      }
      lacc[0] = __builtin_amdgcn_mfma_f32_16x16x32_bf16(pa0, ones, lacc[0], 0, 0, 0);
      lacc[1] = __builtin_amdgcn_mfma_f32_16x16x32_bf16(pa1, ones, lacc[1], 0, 0, 0);
    }
    __syncthreads();
  }

  // partial write: rows m0 + qs*16 + quad*4 + r, col d = nt2*16 + fr
  unsigned short* Oc = Opart + (size_t)c * (NBH * TT * DD) + head_base;
#pragma unroll
  for (int qs = 0; qs < 2; qs++) {
#pragma unroll
    for (int nt2 = 0; nt2 < 8; nt2++)
#pragma unroll
      for (int r = 0; r < 4; r++)
        Oc[(size_t)(m0 + qs * 16 + quad * 4 + r) * DD + nt2 * 16 + fr] = f2b(oacc[qs][nt2][r]);
    if (fr == 0) {
#pragma unroll
      for (int r = 0; r < 4; r++)
        lpart[c * (NBH * TT) + bh * TT + m0 + qs * 16 + quad * 4 + r] = lacc[qs][r];
    }
  }
}

// ---------------- combine: yb = (sum_c O_c)/(sum_c l_c), bf16 [bt][C] ----------
__global__ __launch_bounds__(256) void combine_kernel(const unsigned short* __restrict__ Opart,
                                                      const float* __restrict__ lpart,
                                                      unsigned short* __restrict__ yb) {
  int idx = blockIdx.x * 256 + threadIdx.x;    // 1,572,864 threads, 4 elems each
  int row = idx >> 5;                          // bh*2048 + t
  int dg = (idx & 31) * 4;
  int t = row & 2047;
  int qt = t >> 7;                             // 128-row blocks
  int nc = (4 * qt + 4 + 15) >> 4;             // chunks written for this row

  float a0 = 0.f, a1 = 0.f, a2 = 0.f, a3 = 0.f, l = 0.f;
  for (int cchunk = 0; cchunk < nc; cchunk++) {
    ushort4 o = *(const ushort4*)&Opart[(size_t)cchunk * (NBH * TT * DD) + (size_t)row * DD + dg];
    a0 += b2f(o.x); a1 += b2f(o.y); a2 += b2f(o.z); a3 += b2f(o.w);
    l += lpart[cchunk * (NBH * TT) + row];
  }
  float linv = 1.f / l;
  int bh = row >> 11;
  int b = bh / HH, h = bh % HH;
  ushort4 u = { f2b(a0 * linv), f2b(a1 * linv), f2b(a2 * linv), f2b(a3 * linv) };
  *(ushort4*)&yb[((size_t)(b * TT + t)) * CC + h * DD + dg] = u;
}

// ---------------- launch ----------------
extern "C" void kernel_launch(void* const* d_in, const int* in_sizes, int n_in,
                              void* d_out, int out_size, void* d_ws, size_t ws_size,
                              hipStream_t stream) {
  const float* x     = (const float*)d_in[0];
  const float* cosb  = (const float*)d_in[1];
  const float* sinb  = (const float*)d_in[2];
  const float* wq    = (const float*)d_in[3];
  const float* wk    = (const float*)d_in[4];
  const float* wv    = (const float*)d_in[5];
  const float* wproj = (const float*)d_in[6];
  float* out = (float*)d_out;

  // workspace layout (117,964,800 B exactly):
  //   0         : q_t bf16 [bh][t][d] (12,582,912)
  //   12582912  : k_t bf16 [bh][t][d] (12,582,912)
  //   25165824  : v_t bf16 [bh][d][t] (12,582,912)
  //   37748736  : yb  bf16 [bt][C]    (12,582,912)
  //   50331648  : xb  bf16 (12,582,912) -> dead after gemm_qkv -> lpart (786,432)
  //   62914560  : wb  bf16 4x589824 elems (4,718,592)
  //   67633152  : Opart bf16 4 chunks x [bh][t][d] (50,331,648)
  char* w = (char*)d_ws;
  unsigned short* q_t   = (unsigned short*)(w);
  unsigned short* k_t   = (unsigned short*)(w + 12582912);
  unsigned short* v_t   = (unsigned short*)(w + 25165824);
  unsigned short* yb    = (unsigned short*)(w + 37748736);
  unsigned short* xb    = (unsigned short*)(w + 50331648);
  float*          lpart = (float*)(w + 50331648);   // alias xb (dead after gemm_qkv)
  unsigned short* wb    = (unsigned short*)(w + 62914560);
  unsigned short* Opart = (unsigned short*)(w + 67633152);

  cvt_all_kernel<<<8448, 256, 0, stream>>>(x, wq, wk, wv, wproj, xb, wb);

  gemm_qkv<<<dim3(BT / 128, 3 * HH), 256, 0, stream>>>(xb, wb, q_t, k_t, v_t);

  rope_all_kernel<<<24576, 256, 0, stream>>>(q_t, k_t, cosb, sinb);

  attn_mfma<<<960, 256, 0, stream>>>(q_t, k_t, v_t, Opart, lpart);
  combine_kernel<<<6144, 256, 0, stream>>>(Opart, lpart, yb);

  gemm_w64<<<dim3(BT / 64, CC / 128), 256, 0, stream>>>(yb, wb + 3 * 589824, out);
}